// Round 2
// baseline (179.255 us; speedup 1.0000x reference)
//
#include <hip/hip_runtime.h>
#include <hip/hip_bf16.h>
#include <math.h>

#define N_TOK 4096
#define DIM   1024

typedef __attribute__((ext_vector_type(8))) short s16x8;
typedef __attribute__((ext_vector_type(4))) float f32x4;

__device__ inline short to_bf16(float f) {
  union { float f; unsigned u; } v; v.f = f;
  unsigned r = v.u + 0x7FFFu + ((v.u >> 16) & 1u);   // RNE
  return (short)(r >> 16);
}

__device__ inline void gload16(const short* g, short* l) {
  __builtin_amdgcn_global_load_lds(
      (const __attribute__((address_space(1))) unsigned int*)g,
      (__attribute__((address_space(3))) unsigned int*)l, 16, 0, 0);
}

__device__ inline void bar() {
  asm volatile("" ::: "memory");
  __builtin_amdgcn_s_barrier();
  asm volatile("" ::: "memory");
}

// ---------------- cast fp32 -> bf16 ----------------
__global__ void cast_bf16_kernel(const float* __restrict__ in, short* __restrict__ out, int n) {
  int i = (blockIdx.x * blockDim.x + threadIdx.x) * 4;
  if (i >= n) return;
  float4 v = *reinterpret_cast<const float4*>(in + i);
  short4 o;
  o.x = to_bf16(v.x); o.y = to_bf16(v.y); o.z = to_bf16(v.z); o.w = to_bf16(v.w);
  *reinterpret_cast<short4*>(out + i) = o;
}

// ---------------- transpose + cast: in[R][C] fp32 -> out[C][R] bf16 ----------------
__global__ void transpose_cast_kernel(const float* __restrict__ in, short* __restrict__ out,
                                      int R, int C) {
  __shared__ float tile[32][33];
  int bx = blockIdx.x * 32, by = blockIdx.y * 32;
  int tx = threadIdx.x, ty = threadIdx.y;   // block (32,8)
  #pragma unroll
  for (int i = 0; i < 32; i += 8)
    tile[ty + i][tx] = in[(size_t)(by + ty + i) * C + (bx + tx)];
  __syncthreads();
  #pragma unroll
  for (int i = 0; i < 32; i += 8)
    out[(size_t)(bx + ty + i) * R + (by + tx)] = to_bf16(tile[tx][ty + i]);
}

// fast tanh via exp2-based __expf: 1 - 2/(e^{2x}+1). Correct limits at +/-inf.
__device__ inline float fast_tanh(float x) {
  float e = __expf(2.0f * x);
  return 1.0f - 2.0f / (e + 1.0f);
}

// ================= 256x256 tile, BK=32, 3-buffer counted-vmcnt pipeline ==========
// Computes P = exp(tanh(A B^T) * scale) (bf16) + atomic rowsum.
// A [M,K], B [N,K] row-major bf16. Grid = (M/256)*(N/256) 1-D, block = 512.
__global__ __launch_bounds__(512, 2)
void gemm256_p(const short* __restrict__ A, const short* __restrict__ B,
               short* __restrict__ P, float* __restrict__ rowsum,
               int K, int ldc, int nbx, float scale)
{
  __shared__ short lds[3 * 16384];     // 3 bufs x (A 256x32 + B 256x32) bf16 = 96 KB
  const int t    = threadIdx.x;
  const int lane = t & 63;
  const int w    = t >> 6;             // 8 waves: 2 (M) x 4 (N)
  const int wr   = w >> 2, wc = w & 3;
  const int l15  = lane & 15, l4 = lane >> 4;

  // bijective XCD swizzle (gridDim.x % 8 == 0)
  const int b   = blockIdx.x;
  const int swz = (b & 7) * ((int)gridDim.x >> 3) + (b >> 3);
  const int bxx = swz % nbx, byy = swz / nbx;

  const int NT = K >> 5;

  // staging: per half-tile (16 KB) 16 segments of 1024 B; wave w owns segs w*2, w*2+1.
  // lane writes seg_base + lane*16 -> row = seg*16 + (lane>>2), 16B col chunk = lane&3.
  const int srow = lane >> 2;
  const int scol = (lane & 3) * 8;
  const short* gA0 = A + (size_t)(byy * 256 + (w * 2 + 0) * 16 + srow) * K + scol;
  const short* gA1 = A + (size_t)(byy * 256 + (w * 2 + 1) * 16 + srow) * K + scol;
  const short* gB0 = B + (size_t)(bxx * 256 + (w * 2 + 0) * 16 + srow) * K + scol;
  const short* gB1 = B + (size_t)(bxx * 256 + (w * 2 + 1) * 16 + srow) * K + scol;

  const int sA0 = (w * 2 + 0) * 512, sA1 = (w * 2 + 1) * 512;   // shorts
  const int sB0 = 8192 + sA0,        sB1 = 8192 + sA1;

  f32x4 acc[8][4];
  #pragma unroll
  for (int m = 0; m < 8; ++m)
    #pragma unroll
    for (int n = 0; n < 4; ++n)
      acc[m][n] = f32x4{0.f, 0.f, 0.f, 0.f};

  // prologue: stage K-tiles 0 and 1 (buffers 0, 1); keep tile 1 partially in flight
  gload16(gA0, &lds[0 + sA0]);  gload16(gA1, &lds[0 + sA1]);
  gload16(gB0, &lds[0 + sB0]);  gload16(gB1, &lds[0 + sB1]);
  gA0 += 32; gA1 += 32; gB0 += 32; gB1 += 32;
  gload16(gA0, &lds[16384 + sA0]);  gload16(gA1, &lds[16384 + sA1]);
  gload16(gB0, &lds[16384 + sB0]);  gload16(gB1, &lds[16384 + sB1]);
  gA0 += 32; gA1 += 32; gB0 += 32; gB1 += 32;
  asm volatile("s_waitcnt vmcnt(4)" ::: "memory");   // tile 0 landed; tile 1 in flight
  bar();

  for (int kt = 0; kt < NT; ++kt) {
    const int bufo = (kt % 3) * 16384;
    const int stg  = ((kt + 2) % 3) * 16384;
    const bool do_stage = (kt + 2) < NT;

    s16x8 af[4], bf[4];
    // -------- phase 1: read A m0-3 + B n0-3, stage A(kt+2), MFMA quad 1 --------
    #pragma unroll
    for (int m = 0; m < 4; ++m)
      af[m] = *(const s16x8*)&lds[bufo + (wr * 128 + m * 16 + l15) * 32 + l4 * 8];
    #pragma unroll
    for (int n = 0; n < 4; ++n)
      bf[n] = *(const s16x8*)&lds[bufo + 8192 + (wc * 64 + n * 16 + l15) * 32 + l4 * 8];
    if (do_stage) {
      gload16(gA0, &lds[stg + sA0]);
      gload16(gA1, &lds[stg + sA1]);
    }
    gA0 += 32; gA1 += 32;
    bar();
    __builtin_amdgcn_s_setprio(1);
    #pragma unroll
    for (int m = 0; m < 4; ++m)
      #pragma unroll
      for (int n = 0; n < 4; ++n)
        acc[m][n] = __builtin_amdgcn_mfma_f32_16x16x32_bf16(af[m], bf[n], acc[m][n], 0, 0, 0);
    __builtin_amdgcn_s_setprio(0);
    bar();
    // -------- phase 2: read A m4-7 (reuse B), stage B(kt+2), MFMA quad 2 --------
    #pragma unroll
    for (int m = 0; m < 4; ++m)
      af[m] = *(const s16x8*)&lds[bufo + (wr * 128 + (m + 4) * 16 + l15) * 32 + l4 * 8];
    if (do_stage) {
      gload16(gB0, &lds[stg + sB0]);
      gload16(gB1, &lds[stg + sB1]);
    }
    gB0 += 32; gB1 += 32;
    bar();
    __builtin_amdgcn_s_setprio(1);
    #pragma unroll
    for (int m = 0; m < 4; ++m)
      #pragma unroll
      for (int n = 0; n < 4; ++n)
        acc[m + 4][n] = __builtin_amdgcn_mfma_f32_16x16x32_bf16(af[m], bf[n], acc[m + 4][n], 0, 0, 0);
    __builtin_amdgcn_s_setprio(0);
    // counted wait: allow the 4 loads of tile kt+2 to stay in flight across the barrier
    if (do_stage) asm volatile("s_waitcnt vmcnt(4)" ::: "memory");
    else          asm volatile("s_waitcnt vmcnt(0)" ::: "memory");
    bar();
  }

  // -------- epilogue: p = exp(tanh(acc)*scale), bf16 store + atomic rowsum --------
  const int rbase = byy * 256 + wr * 128;
  const int cbase = bxx * 256 + wc * 64;
  #pragma unroll
  for (int m = 0; m < 8; ++m) {
    #pragma unroll
    for (int r = 0; r < 4; ++r) {
      const int grow = rbase + m * 16 + l4 * 4 + r;
      float rs = 0.f;
      #pragma unroll
      for (int n = 0; n < 4; ++n) {
        float p = __expf(fast_tanh(acc[m][n][r]) * scale);
        rs += p;
        P[(size_t)grow * ldc + (cbase + n * 16 + l15)] = to_bf16(p);
      }
      rs += __shfl_xor(rs, 1);
      rs += __shfl_xor(rs, 2);
      rs += __shfl_xor(rs, 4);
      rs += __shfl_xor(rs, 8);
      if (l15 == 0) atomicAdd(&rowsum[grow], rs);
    }
  }
}

// ---------------- NT GEMM: C[M][N] = A[M,K] * B[N,K]^T + epilogue ----------------
// EPI 0: + bias[col], store bf16
// EPI 1: + bias[row], store bf16
// EPI 3: acc / l[row], store fp32
template<int EPI>
__global__ __launch_bounds__(256, 2)
void gemm_nt(const short* __restrict__ A, const short* __restrict__ B,
             const float* __restrict__ aux, short* __restrict__ Cb,
             float* __restrict__ Cf, float* __restrict__ rowsum,
             int M, int N, int K, float scale)
{
  __shared__ short As[128 * 64];
  __shared__ short Bs[128 * 64];
  const int t    = threadIdx.x;
  const int lane = t & 63;
  const int wid  = t >> 6;          // 4 waves
  const int wr   = wid >> 1, wc = wid & 1;
  const int l15  = lane & 15, l4 = lane >> 4;

  const short* Abase = A + (size_t)blockIdx.y * 128 * K;
  const short* Bbase = B + (size_t)blockIdx.x * 128 * K;

  f32x4 acc[4][4];
  #pragma unroll
  for (int m = 0; m < 4; ++m)
    #pragma unroll
    for (int n = 0; n < 4; ++n)
      acc[m][n] = f32x4{0.f, 0.f, 0.f, 0.f};

  int rowi[4], sli[4];
  #pragma unroll
  for (int i = 0; i < 4; ++i) { int s = t + i * 256; rowi[i] = s >> 3; sli[i] = s & 7; }

  s16x8 ra[4], rb[4];
  const int nk = K >> 6;
  #pragma unroll
  for (int i = 0; i < 4; ++i) {
    ra[i] = *(const s16x8*)(Abase + (size_t)rowi[i] * K + sli[i] * 8);
    rb[i] = *(const s16x8*)(Bbase + (size_t)rowi[i] * K + sli[i] * 8);
  }

  for (int kt = 0; kt < nk; ++kt) {
    __syncthreads();
    #pragma unroll
    for (int i = 0; i < 4; ++i) {
      int ps = sli[i] ^ (rowi[i] & 7);
      *(s16x8*)(&As[rowi[i] * 64 + ps * 8]) = ra[i];
      *(s16x8*)(&Bs[rowi[i] * 64 + ps * 8]) = rb[i];
    }
    __syncthreads();
    if (kt + 1 < nk) {
      const int ko = (kt + 1) * 64;
      #pragma unroll
      for (int i = 0; i < 4; ++i) {
        ra[i] = *(const s16x8*)(Abase + (size_t)rowi[i] * K + ko + sli[i] * 8);
        rb[i] = *(const s16x8*)(Bbase + (size_t)rowi[i] * K + ko + sli[i] * 8);
      }
    }
    #pragma unroll
    for (int kk = 0; kk < 2; ++kk) {
      s16x8 af[4], bfv[4];
      #pragma unroll
      for (int m = 0; m < 4; ++m) {
        int row = wr * 64 + m * 16 + l15;
        int ps  = (kk * 4 + l4) ^ (row & 7);
        af[m] = *(const s16x8*)(&As[row * 64 + ps * 8]);
      }
      #pragma unroll
      for (int n = 0; n < 4; ++n) {
        int row = wc * 64 + n * 16 + l15;
        int ps  = (kk * 4 + l4) ^ (row & 7);
        bfv[n] = *(const s16x8*)(&Bs[row * 64 + ps * 8]);
      }
      #pragma unroll
      for (int m = 0; m < 4; ++m)
        #pragma unroll
        for (int n = 0; n < 4; ++n)
          acc[m][n] = __builtin_amdgcn_mfma_f32_16x16x32_bf16(af[m], bfv[n], acc[m][n], 0, 0, 0);
    }
  }

  const int rbase = blockIdx.y * 128 + wr * 64;
  const int cbase = blockIdx.x * 128 + wc * 64;

  #pragma unroll
  for (int m = 0; m < 4; ++m) {
    #pragma unroll
    for (int r = 0; r < 4; ++r) {
      const int grow = rbase + m * 16 + l4 * 4 + r;
      if (EPI == 3) {
        const float invl = 1.f / aux[grow];
        #pragma unroll
        for (int n = 0; n < 4; ++n)
          Cf[(size_t)grow * N + (cbase + n * 16 + l15)] = acc[m][n][r] * invl;
      } else {
        #pragma unroll
        for (int n = 0; n < 4; ++n) {
          const int gcol = cbase + n * 16 + l15;
          const float bias = (EPI == 0) ? aux[gcol] : aux[grow];
          Cb[(size_t)grow * N + gcol] = to_bf16(acc[m][n][r] + bias);
        }
      }
    }
  }
}

extern "C" void kernel_launch(void* const* d_in, const int* in_sizes, int n_in,
                              void* d_out, int out_size, void* d_ws, size_t ws_size,
                              hipStream_t stream) {
  const float* x  = (const float*)d_in[0];
  const float* Wq = (const float*)d_in[1];
  const float* bq = (const float*)d_in[2];
  const float* Wk = (const float*)d_in[3];
  const float* bk = (const float*)d_in[4];
  const float* Wv = (const float*)d_in[5];
  const float* bv = (const float*)d_in[6];
  float* out = (float*)d_out;

  char* ws = (char*)d_ws;
  short* xb   = (short*)(ws);                      //  8 MB  x bf16 [4096][1024]
  short* qb   = (short*)(ws + (8ull  << 20));      //  8 MB
  short* kb   = (short*)(ws + (16ull << 20));      //  8 MB
  short* vTb  = (short*)(ws + (24ull << 20));      //  8 MB  v^T [1024][4096]
  short* WqT  = (short*)(ws + (32ull << 20));      //  2 MB
  short* WkT  = (short*)(ws + (34ull << 20));      //  2 MB
  short* WvT  = (short*)(ws + (36ull << 20));      //  2 MB
  float* lsum = (float*)(ws + (38ull << 20));      // 16 KB
  short* P    = (short*)(ws + (40ull << 20));      // 32 MB  P bf16 [4096][4096]

  hipMemsetAsync(lsum, 0, N_TOK * sizeof(float), stream);

  cast_bf16_kernel<<<(N_TOK * DIM / 4 + 255) / 256, 256, 0, stream>>>(x, xb, N_TOK * DIM);
  dim3 tgrid(DIM / 32, DIM / 32), tblk(32, 8);
  transpose_cast_kernel<<<tgrid, tblk, 0, stream>>>(Wq, WqT, DIM, DIM);
  transpose_cast_kernel<<<tgrid, tblk, 0, stream>>>(Wk, WkT, DIM, DIM);
  transpose_cast_kernel<<<tgrid, tblk, 0, stream>>>(Wv, WvT, DIM, DIM);

  dim3 blk(256);
  // q = x@Wq + bq ; k = x@Wk + bk   (M=4096, N=1024, K=1024)
  gemm_nt<0><<<dim3(DIM / 128, N_TOK / 128), blk, 0, stream>>>(
      xb, WqT, bq, qb, nullptr, nullptr, N_TOK, DIM, DIM, 0.f);
  gemm_nt<0><<<dim3(DIM / 128, N_TOK / 128), blk, 0, stream>>>(
      xb, WkT, bk, kb, nullptr, nullptr, N_TOK, DIM, DIM, 0.f);
  // vT[j][i] = sum_kk WvT[j][kk]*x[i][kk] + bv[j]   (M=1024, N=4096, K=1024)
  gemm_nt<1><<<dim3(N_TOK / 128, DIM / 128), blk, 0, stream>>>(
      WvT, xb, bv, vTb, nullptr, nullptr, DIM, N_TOK, DIM, 0.f);
  // P = exp(tanh(q k^T) * 1/32), rowsum -> lsum   (M=N=4096, K=1024) — new 256^2 pipeline
  gemm256_p<<<dim3((N_TOK / 256) * (N_TOK / 256)), dim3(512), 0, stream>>>(
      qb, kb, P, lsum, DIM, N_TOK, N_TOK / 256, 0.03125f);
  // out = (P @ v) / lsum[row]   (M=4096, N=1024, K=4096)
  gemm_nt<3><<<dim3(DIM / 128, N_TOK / 128), blk, 0, stream>>>(
      P, vTb, lsum, nullptr, out, nullptr, N_TOK, DIM, N_TOK, 0.f);
}

// Round 3
// 165.141 us; speedup vs baseline: 1.0855x; 1.0855x over previous
//
#include <hip/hip_runtime.h>
#include <hip/hip_bf16.h>
#include <math.h>

#define N_TOK 4096
#define DIM   1024

typedef __attribute__((ext_vector_type(8))) short s16x8;
typedef __attribute__((ext_vector_type(4))) float f32x4;

__device__ inline short to_bf16(float f) {
  union { float f; unsigned u; } v; v.f = f;
  unsigned r = v.u + 0x7FFFu + ((v.u >> 16) & 1u);   // RNE
  return (short)(r >> 16);
}

__device__ inline void gload16(const short* g, short* l) {
  __builtin_amdgcn_global_load_lds(
      (const __attribute__((address_space(1))) unsigned int*)g,
      (__attribute__((address_space(3))) unsigned int*)l, 16, 0, 0);
}

__device__ inline void bar() {
  asm volatile("" ::: "memory");
  __builtin_amdgcn_s_barrier();
  asm volatile("" ::: "memory");
}

// ---------------- cast fp32 -> bf16 ----------------
__global__ void cast_bf16_kernel(const float* __restrict__ in, short* __restrict__ out, int n) {
  int i = (blockIdx.x * blockDim.x + threadIdx.x) * 4;
  if (i >= n) return;
  float4 v = *reinterpret_cast<const float4*>(in + i);
  short4 o;
  o.x = to_bf16(v.x); o.y = to_bf16(v.y); o.z = to_bf16(v.z); o.w = to_bf16(v.w);
  *reinterpret_cast<short4*>(out + i) = o;
}

// ---------------- transpose + cast: in[R][C] fp32 -> out[C][R] bf16 ----------------
__global__ void transpose_cast_kernel(const float* __restrict__ in, short* __restrict__ out,
                                      int R, int C) {
  __shared__ float tile[32][33];
  int bx = blockIdx.x * 32, by = blockIdx.y * 32;
  int tx = threadIdx.x, ty = threadIdx.y;   // block (32,8)
  #pragma unroll
  for (int i = 0; i < 32; i += 8)
    tile[ty + i][tx] = in[(size_t)(by + ty + i) * C + (bx + tx)];
  __syncthreads();
  #pragma unroll
  for (int i = 0; i < 32; i += 8)
    out[(size_t)(bx + ty + i) * R + (by + tx)] = to_bf16(tile[tx][ty + i]);
}

__device__ inline float fast_tanh(float x) {
  float e = __expf(2.0f * x);
  return 1.0f - 2.0f / (e + 1.0f);
}

// ================= 256x256 tile, BK=32, 3-buffer counted-vmcnt pipeline ==========
// EPI 0: P = exp(tanh(A B^T) * 1/32) bf16 (ld N_TOK) + atomic rowsum. grid 256 = 16x16.
// EPI 1: PV split-K=4. grid 256 = 16(M) x 4(N) x 4(Kchunk).
//        mode 1: partial fp32 -> part[kc]; mode 0: atomicAdd(out, acc*invl).
// Chunk swizzle: data chunk c of row r lives at physical chunk c ^ ((r>>1)&3).
// Staging keeps linear LDS dest; the global SOURCE chunk is pre-swizzled per lane.
template<int EPI>
__global__ __launch_bounds__(512, 2)
void gemm256(const short* __restrict__ A, const short* __restrict__ B,
             int lda, int ldb,
             short* __restrict__ Pout, float* __restrict__ rowsum,
             float* __restrict__ outF, const float* __restrict__ lsum,
             float* __restrict__ part, int mode)
{
  __shared__ short lds[3 * 16384];     // 3 bufs x (A 256x32 + B 256x32) bf16 = 96 KB
  const int t    = threadIdx.x;
  const int lane = t & 63;
  const int w    = t >> 6;             // 8 waves: 2 (M) x 4 (N)
  const int wr   = w >> 2, wc = w & 3;
  const int l15  = lane & 15, l4 = lane >> 4;

  // bijective XCD swizzle (grid = 256)
  const int b   = blockIdx.x;
  const int swz = (b & 7) * 32 + (b >> 3);
  int bxx, byy, koff;
  if (EPI == 0) { bxx = swz & 15; byy = swz >> 4; koff = 0; }
  else          { koff = (swz & 3) << 10; bxx = (swz >> 2) & 3; byy = swz >> 4; }

  const int NT = 32;                   // 1024 K per block, BK=32

  // staging: wave w owns segs w*2, w*2+1 (16 rows x 64 B each); linear LDS dest.
  const int srow = lane >> 2;
  const int ssc  = ((lane & 3) ^ ((lane >> 3) & 3)) * 8;   // pre-swizzled source chunk
  const short* gA0 = A + (size_t)(byy * 256 + (w * 2 + 0) * 16 + srow) * lda + koff + ssc;
  const short* gA1 = A + (size_t)(byy * 256 + (w * 2 + 1) * 16 + srow) * lda + koff + ssc;
  const short* gB0 = B + (size_t)(bxx * 256 + (w * 2 + 0) * 16 + srow) * ldb + koff + ssc;
  const short* gB1 = B + (size_t)(bxx * 256 + (w * 2 + 1) * 16 + srow) * ldb + koff + ssc;

  const int sA0 = (w * 2 + 0) * 512, sA1 = (w * 2 + 1) * 512;   // shorts
  const int sB0 = 8192 + sA0,        sB1 = 8192 + sA1;

  f32x4 acc[8][4];
  #pragma unroll
  for (int m = 0; m < 8; ++m)
    #pragma unroll
    for (int n = 0; n < 4; ++n)
      acc[m][n] = f32x4{0.f, 0.f, 0.f, 0.f};

  // read-side swizzled chunk offset (shorts): depends only on lane
  const int rch = (l4 ^ ((lane >> 1) & 3)) * 8;

  // prologue: stage K-tiles 0 and 1
  gload16(gA0, &lds[0 + sA0]);  gload16(gA1, &lds[0 + sA1]);
  gload16(gB0, &lds[0 + sB0]);  gload16(gB1, &lds[0 + sB1]);
  gA0 += 32; gA1 += 32; gB0 += 32; gB1 += 32;
  gload16(gA0, &lds[16384 + sA0]);  gload16(gA1, &lds[16384 + sA1]);
  gload16(gB0, &lds[16384 + sB0]);  gload16(gB1, &lds[16384 + sB1]);
  gA0 += 32; gA1 += 32; gB0 += 32; gB1 += 32;
  asm volatile("s_waitcnt vmcnt(4)" ::: "memory");
  bar();

  for (int kt = 0; kt < NT; ++kt) {
    const int bufo = (kt % 3) * 16384;
    const int stg  = ((kt + 2) % 3) * 16384;
    const bool do_stage = (kt + 2) < NT;

    s16x8 af[4], bf[4];
    // -------- phase 1: read A m0-3 + B n0-3, stage A(kt+2), MFMA quad 1 --------
    #pragma unroll
    for (int m = 0; m < 4; ++m)
      af[m] = *(const s16x8*)&lds[bufo + (wr * 128 + m * 16 + l15) * 32 + rch];
    #pragma unroll
    for (int n = 0; n < 4; ++n)
      bf[n] = *(const s16x8*)&lds[bufo + 8192 + (wc * 64 + n * 16 + l15) * 32 + rch];
    if (do_stage) {
      gload16(gA0, &lds[stg + sA0]);
      gload16(gA1, &lds[stg + sA1]);
    }
    gA0 += 32; gA1 += 32;
    bar();
    __builtin_amdgcn_s_setprio(1);
    #pragma unroll
    for (int m = 0; m < 4; ++m)
      #pragma unroll
      for (int n = 0; n < 4; ++n)
        acc[m][n] = __builtin_amdgcn_mfma_f32_16x16x32_bf16(af[m], bf[n], acc[m][n], 0, 0, 0);
    __builtin_amdgcn_s_setprio(0);
    bar();
    // -------- phase 2: read A m4-7 (reuse B), stage B(kt+2), MFMA quad 2 --------
    #pragma unroll
    for (int m = 0; m < 4; ++m)
      af[m] = *(const s16x8*)&lds[bufo + (wr * 128 + (m + 4) * 16 + l15) * 32 + rch];
    if (do_stage) {
      gload16(gB0, &lds[stg + sB0]);
      gload16(gB1, &lds[stg + sB1]);
    }
    gB0 += 32; gB1 += 32;
    bar();
    __builtin_amdgcn_s_setprio(1);
    #pragma unroll
    for (int m = 0; m < 4; ++m)
      #pragma unroll
      for (int n = 0; n < 4; ++n)
        acc[m + 4][n] = __builtin_amdgcn_mfma_f32_16x16x32_bf16(af[m], bf[n], acc[m + 4][n], 0, 0, 0);
    __builtin_amdgcn_s_setprio(0);
    if (do_stage) asm volatile("s_waitcnt vmcnt(4)" ::: "memory");
    else          asm volatile("s_waitcnt vmcnt(0)" ::: "memory");
    bar();
  }

  const int rbase = byy * 256 + wr * 128;
  const int cbase = bxx * 256 + wc * 64;

  if (EPI == 0) {
    #pragma unroll
    for (int m = 0; m < 8; ++m) {
      #pragma unroll
      for (int r = 0; r < 4; ++r) {
        const int grow = rbase + m * 16 + l4 * 4 + r;
        float rs = 0.f;
        #pragma unroll
        for (int n = 0; n < 4; ++n) {
          float p = __expf(fast_tanh(acc[m][n][r]) * 0.03125f);
          rs += p;
          Pout[(size_t)grow * N_TOK + (cbase + n * 16 + l15)] = to_bf16(p);
        }
        rs += __shfl_xor(rs, 1);
        rs += __shfl_xor(rs, 2);
        rs += __shfl_xor(rs, 4);
        rs += __shfl_xor(rs, 8);
        if (l15 == 0) atomicAdd(&rowsum[grow], rs);
      }
    }
  } else {
    const int kc = koff >> 10;
    float* pdst = part + (size_t)kc * (N_TOK * DIM);
    #pragma unroll
    for (int m = 0; m < 8; ++m) {
      #pragma unroll
      for (int r = 0; r < 4; ++r) {
        const int grow = rbase + m * 16 + l4 * 4 + r;
        if (mode) {
          #pragma unroll
          for (int n = 0; n < 4; ++n)
            pdst[(size_t)grow * DIM + (cbase + n * 16 + l15)] = acc[m][n][r];
        } else {
          const float invl = 1.f / lsum[grow];
          #pragma unroll
          for (int n = 0; n < 4; ++n)
            atomicAdd(&outF[(size_t)grow * DIM + (cbase + n * 16 + l15)], acc[m][n][r] * invl);
        }
      }
    }
  }
}

// ---------------- reduce: out = (p0+p1+p2+p3) / lsum[row] ----------------
__global__ void reduce_pv(const float* __restrict__ part, const float* __restrict__ lsum,
                          float* __restrict__ out) {
  const int i = blockIdx.x * blockDim.x + threadIdx.x;   // float4 index, DIM/4=256 per row
  const float4* p0 = (const float4*)part;
  const float4* p1 = p0 + (N_TOK * DIM / 4);
  const float4* p2 = p1 + (N_TOK * DIM / 4);
  const float4* p3 = p2 + (N_TOK * DIM / 4);
  float4 a = p0[i], b = p1[i], c = p2[i], d = p3[i];
  const float invl = 1.f / lsum[i >> 8];
  float4 o;
  o.x = (a.x + b.x + c.x + d.x) * invl;
  o.y = (a.y + b.y + c.y + d.y) * invl;
  o.z = (a.z + b.z + c.z + d.z) * invl;
  o.w = (a.w + b.w + c.w + d.w) * invl;
  ((float4*)out)[i] = o;
}

// ---------------- 128^2 NT GEMM (projections) ----------------
// EPI 0: + bias[col], store bf16 ; EPI 1: + bias[row], store bf16
template<int EPI>
__global__ __launch_bounds__(256, 2)
void gemm_nt(const short* __restrict__ A, const short* __restrict__ B,
             const float* __restrict__ aux, short* __restrict__ Cb,
             int M, int N, int K)
{
  __shared__ short As[128 * 64];
  __shared__ short Bs[128 * 64];
  const int t    = threadIdx.x;
  const int lane = t & 63;
  const int wid  = t >> 6;
  const int wr   = wid >> 1, wc = wid & 1;
  const int l15  = lane & 15, l4 = lane >> 4;

  const short* Abase = A + (size_t)blockIdx.y * 128 * K;
  const short* Bbase = B + (size_t)blockIdx.x * 128 * K;

  f32x4 acc[4][4];
  #pragma unroll
  for (int m = 0; m < 4; ++m)
    #pragma unroll
    for (int n = 0; n < 4; ++n)
      acc[m][n] = f32x4{0.f, 0.f, 0.f, 0.f};

  int rowi[4], sli[4];
  #pragma unroll
  for (int i = 0; i < 4; ++i) { int s = t + i * 256; rowi[i] = s >> 3; sli[i] = s & 7; }

  s16x8 ra[4], rb[4];
  const int nk = K >> 6;
  #pragma unroll
  for (int i = 0; i < 4; ++i) {
    ra[i] = *(const s16x8*)(Abase + (size_t)rowi[i] * K + sli[i] * 8);
    rb[i] = *(const s16x8*)(Bbase + (size_t)rowi[i] * K + sli[i] * 8);
  }

  for (int kt = 0; kt < nk; ++kt) {
    __syncthreads();
    #pragma unroll
    for (int i = 0; i < 4; ++i) {
      int ps = sli[i] ^ (rowi[i] & 7);
      *(s16x8*)(&As[rowi[i] * 64 + ps * 8]) = ra[i];
      *(s16x8*)(&Bs[rowi[i] * 64 + ps * 8]) = rb[i];
    }
    __syncthreads();
    if (kt + 1 < nk) {
      const int ko = (kt + 1) * 64;
      #pragma unroll
      for (int i = 0; i < 4; ++i) {
        ra[i] = *(const s16x8*)(Abase + (size_t)rowi[i] * K + ko + sli[i] * 8);
        rb[i] = *(const s16x8*)(Bbase + (size_t)rowi[i] * K + ko + sli[i] * 8);
      }
    }
    #pragma unroll
    for (int kk = 0; kk < 2; ++kk) {
      s16x8 af[4], bfv[4];
      #pragma unroll
      for (int m = 0; m < 4; ++m) {
        int row = wr * 64 + m * 16 + l15;
        int ps  = (kk * 4 + l4) ^ (row & 7);
        af[m] = *(const s16x8*)(&As[row * 64 + ps * 8]);
      }
      #pragma unroll
      for (int n = 0; n < 4; ++n) {
        int row = wc * 64 + n * 16 + l15;
        int ps  = (kk * 4 + l4) ^ (row & 7);
        bfv[n] = *(const s16x8*)(&Bs[row * 64 + ps * 8]);
      }
      #pragma unroll
      for (int m = 0; m < 4; ++m)
        #pragma unroll
        for (int n = 0; n < 4; ++n)
          acc[m][n] = __builtin_amdgcn_mfma_f32_16x16x32_bf16(af[m], bfv[n], acc[m][n], 0, 0, 0);
    }
  }

  const int rbase = blockIdx.y * 128 + wr * 64;
  const int cbase = blockIdx.x * 128 + wc * 64;

  #pragma unroll
  for (int m = 0; m < 4; ++m) {
    #pragma unroll
    for (int r = 0; r < 4; ++r) {
      const int grow = rbase + m * 16 + l4 * 4 + r;
      #pragma unroll
      for (int n = 0; n < 4; ++n) {
        const int gcol = cbase + n * 16 + l15;
        const float bias = (EPI == 0) ? aux[gcol] : aux[grow];
        Cb[(size_t)grow * N + gcol] = to_bf16(acc[m][n][r] + bias);
      }
    }
  }
}

extern "C" void kernel_launch(void* const* d_in, const int* in_sizes, int n_in,
                              void* d_out, int out_size, void* d_ws, size_t ws_size,
                              hipStream_t stream) {
  const float* x  = (const float*)d_in[0];
  const float* Wq = (const float*)d_in[1];
  const float* bq = (const float*)d_in[2];
  const float* Wk = (const float*)d_in[3];
  const float* bk = (const float*)d_in[4];
  const float* Wv = (const float*)d_in[5];
  const float* bv = (const float*)d_in[6];
  float* out = (float*)d_out;

  char* ws = (char*)d_ws;
  short* xb   = (short*)(ws);                      //  8 MB  x bf16 [4096][1024]
  short* qk   = (short*)(ws + (8ull  << 20));      // 16 MB  q|k bf16 [4096][2048]
  short* vTb  = (short*)(ws + (24ull << 20));      //  8 MB  v^T [1024][4096]
  short* WqkT = (short*)(ws + (32ull << 20));      //  4 MB  [2048][1024]
  short* WvT  = (short*)(ws + (36ull << 20));      //  2 MB
  float* bqk  = (float*)(ws + (38ull << 20));      //  8 KB
  float* lsum = (float*)(ws + (39ull << 20));      // 16 KB
  short* P    = (short*)(ws + (40ull << 20));      // 32 MB  P bf16 [4096][4096]
  float* part = (float*)(ws + (72ull << 20));      // 67 MB  (optional) 4x[4096][1024] f32

  const size_t need = (72ull << 20) + 4ull * N_TOK * DIM * sizeof(float);
  const int mode = (ws_size >= need) ? 1 : 0;      // 1: ws partials + reduce; 0: atomics

  hipMemsetAsync(lsum, 0, N_TOK * sizeof(float), stream);
  if (!mode) hipMemsetAsync(out, 0, (size_t)N_TOK * DIM * sizeof(float), stream);

  hipMemcpyAsync(bqk,        bq, DIM * sizeof(float), hipMemcpyDeviceToDevice, stream);
  hipMemcpyAsync(bqk + DIM,  bk, DIM * sizeof(float), hipMemcpyDeviceToDevice, stream);

  cast_bf16_kernel<<<(N_TOK * DIM / 4 + 255) / 256, 256, 0, stream>>>(x, xb, N_TOK * DIM);
  dim3 tgrid(DIM / 32, DIM / 32), tblk(32, 8);
  transpose_cast_kernel<<<tgrid, tblk, 0, stream>>>(Wq, WqkT, DIM, DIM);
  transpose_cast_kernel<<<tgrid, tblk, 0, stream>>>(Wk, WqkT + DIM * DIM, DIM, DIM);
  transpose_cast_kernel<<<tgrid, tblk, 0, stream>>>(Wv, WvT, DIM, DIM);

  // fused q|k projection: [4096][2048] = x @ [WqT;WkT]^T + bqk
  gemm_nt<0><<<dim3(2 * DIM / 128, N_TOK / 128), dim3(256), 0, stream>>>(
      xb, WqkT, bqk, qk, N_TOK, 2 * DIM, DIM);
  // vT[j][i] = sum_k WvT[j][k]*x[i][k] + bv[j]
  gemm_nt<1><<<dim3(N_TOK / 128, DIM / 128), dim3(256), 0, stream>>>(
      WvT, xb, bv, vTb, DIM, N_TOK, DIM);

  // P = exp(tanh(q k^T)/32) + rowsum
  gemm256<0><<<dim3(256), dim3(512), 0, stream>>>(
      qk, qk + DIM, 2 * DIM, 2 * DIM, P, lsum, nullptr, nullptr, part, mode);
  // PV split-K=4
  gemm256<1><<<dim3(256), dim3(512), 0, stream>>>(
      P, vTb, N_TOK, N_TOK, nullptr, nullptr, out, lsum, part, mode);
  if (mode)
    reduce_pv<<<dim3(N_TOK * DIM / 4 / 256), dim3(256), 0, stream>>>(part, lsum, out);
}